// Round 2
// baseline (171.256 us; speedup 1.0000x reference)
//
#include <hip/hip_runtime.h>
#include <math.h>

#define NSAMP 32768   // 2^15 = 512 * 64
#define NDEL  512
#define NFR   16
#define BATCH 8
#define TWO_PI 6.283185307179586f

__device__ __forceinline__ float2 cmul(float2 a, float2 b) {
    return make_float2(a.x*b.x - a.y*b.y, a.x*b.y + a.y*b.x);
}
__device__ __forceinline__ float2 cadd(float2 a, float2 b){ return make_float2(a.x+b.x, a.y+b.y); }
__device__ __forceinline__ float2 csub(float2 a, float2 b){ return make_float2(a.x-b.x, a.y-b.y); }
// multiply by sign*i : fwd(sign=-1) -> -i*z = (y,-x) ; inv(+1) -> +i*z = (-y,x)
__device__ __forceinline__ float2 crot(float2 z, float sign){ return make_float2(-sign*z.y, sign*z.x); }

// LDS index swizzle to break power-of-2 strides (i -> i + i/8)
__device__ __forceinline__ int phi(int i){ return i + (i >> 3); }

__device__ __forceinline__ void bfly8(const float2 v[8], float sign, float2 X[8]) {
    const float S2 = 0.70710678118654752f;
    float2 t0 = cadd(v[0], v[4]), t1 = csub(v[0], v[4]);
    float2 t2 = cadd(v[2], v[6]), t3 = crot(csub(v[2], v[6]), sign);
    float2 E0 = cadd(t0, t2), E1 = cadd(t1, t3), E2 = csub(t0, t2), E3 = csub(t1, t3);
    float2 u0 = cadd(v[1], v[5]), u1 = csub(v[1], v[5]);
    float2 u2 = cadd(v[3], v[7]), u3 = crot(csub(v[3], v[7]), sign);
    float2 O0 = cadd(u0, u2), O1 = cadd(u1, u3), O2 = csub(u0, u2), O3 = csub(u1, u3);
    float2 c1 = make_float2( S2, sign*S2);
    float2 c3 = make_float2(-S2, sign*S2);
    float2 w1o = cmul(c1, O1);
    float2 w2o = crot(O2, sign);
    float2 w3o = cmul(c3, O3);
    X[0]=cadd(E0,O0);  X[4]=csub(E0,O0);
    X[1]=cadd(E1,w1o); X[5]=csub(E1,w1o);
    X[2]=cadd(E2,w2o); X[6]=csub(E2,w2o);
    X[3]=cadd(E3,w3o); X[7]=csub(E3,w3o);
}

__device__ __forceinline__ void twiddle_q(float2 v[8], float ang1) {
    float sa, ca; __sincosf(ang1, &sa, &ca);
    float2 w1 = make_float2(ca, sa), wq = w1;
#pragma unroll
    for (int q = 1; q < 8; ++q) { v[q] = cmul(v[q], wq); wq = cmul(wq, w1); }
}

// ---------------------------------------------------------------------------
// Kernel 1 (FUSED build + forward 512-FFT): one wave-block per (b, n2) COLUMN
// (samples n = 64*n1 + n2, n1 in [0,512)).  The column layout lets the block
// run the full 512-pt FFT over n1 locally, eliminating the old At global
// round-trip AND one kernel boundary (global sync points are the dominant
// cost here: all four kernels' wave-serial work is ~1-8 µs each by cycle
// arithmetic, yet the pipeline measured 134 µs).
//
//  - softmax weights for ALL 16 frames recomputed per block (coalesced
//    8192-float read of dsel[b]; N(0,1) inputs -> no max-subtraction needed).
//  - divisor sieve by congruence: t | (64*n1+n2)  <=>  n1 = x (mod m),
//    m = t/g, g = gcd(64,t) = 2^lg (needs g | n2); x = (-(n2>>lg)) * inv(2^k)
//    mod m computed by k = 6-lg exact halvings mod odd m.
//    Phase A: the 32 t with m<=8 (>=57 marks) -> block-uniform, lanes split.
//    Phase B: remaining 480 t (m>=9, <=57 marks) -> lane-parallel over t.
//  - damp/S scale depends only on f = n1>>5 -> applied once at FFT load,
//    not per sieve mark.
__global__ void build_fft_kernel(const float* __restrict__ impulse,
                                 const float* __restrict__ dsel,
                                 const float* __restrict__ damping,
                                 const float* __restrict__ noise,
                                 float2* __restrict__ G) {
    const int l  = threadIdx.x;          // 64 threads = 1 wave
    const int b  = blockIdx.x >> 6;
    const int n2 = blockIdx.x & 63;

    __shared__ float  W[16*512];         // raw exp(dsel) per [f][t-1]
    __shared__ float  sc[16];            // damp / S_f
    __shared__ float  dl[512];           // divisor sums over n1 (unscaled)
    __shared__ float2 buf[2][576];       // FFT exchange

    // ---- impulse^2-interp * noise into registers (issue loads early) ----
    float iv[8];
#pragma unroll
    for (int q = 0; q < 8; ++q) {
        int n = 64*l + 4096*q + n2;                  // n = 64*(l+64q) + n2
        float pos = (n + 0.5f) * (1.0f/256.0f) - 0.5f;
        pos = fminf(fmaxf(pos, 0.0f), 127.0f);
        int i0 = (int)pos;
        float w = pos - (float)i0;
        int i1 = (i0 + 1 > 127) ? 127 : i0 + 1;
        float x0 = impulse[b*128 + i0]; x0 *= x0;
        float x1 = impulse[b*128 + i1]; x1 *= x1;
        iv[q] = (x0*(1.0f - w) + x1*w) * noise[b*NSAMP + n];
    }

    // ---- softmax weights, 4 lanes per frame; coalesced dsel reads ----
    // lane l: f = l>>2, handles t-index = (l&3) + 4*i. Per-instruction the 64
    // lanes cover 64 contiguous floats of dsel[b] -> fully coalesced.
    {
        const int f   = l >> 2;
        const int sub = l & 3;
        const float* dp = dsel + b*NDEL*NFR;
        float s = 0.0f;
#pragma unroll 4
        for (int i = 0; i < 128; ++i) {
            int ti = sub + 4*i;                      // delay index = period-1
            float e = __expf(dp[ti*NFR + f]);        // no max-sub: |v| ~ N(0,1)
            W[(f << 9) + ti] = e;
            s += e;
        }
        s += __shfl_xor(s, 1);
        s += __shfl_xor(s, 2);                       // 4-lane group sum = S_f
        float damp = 0.9999f / (1.0f + __expf(-damping[b]));
        if (sub == 0) sc[f] = damp / s;
    }
#pragma unroll
    for (int q = 0; q < 8; ++q) dl[l + 64*q] = 0.0f;
    __syncthreads();

    // ---- Phase A sieve: the 32 periods with m = t/gcd(64,t) <= 8 ----
    // (t, lg = log2 gcd(64,t), m): block-uniform t, lanes split the marks.
    {
        constexpr int TA_t[32]  = {1,2,3,4,5,6,7,8,10,12,14,16,20,24,28,32,
                                   40,48,56,64,80,96,112,128,160,192,224,256,320,384,448,512};
        constexpr int TA_lg[32] = {0,1,0,2,0,1,0,3, 1, 2, 1, 4, 2, 3, 2, 5,
                                    3, 4, 3, 6, 4, 5,  4,  6,  5,  6,  5,  6,  6,  6,  6,  6};
        constexpr int TA_m[32]  = {1,1,3,1,5,3,7,1, 5, 3, 7, 1, 5, 3, 7, 1,
                                    5, 3, 7, 1, 5, 3,  7,  2,  5,  3,  7,  4,  5,  6,  7,  8};
#pragma unroll
        for (int ii = 0; ii < 32; ++ii) {
            const int t = TA_t[ii], lg = TA_lg[ii], m = TA_m[ii];
            if ((n2 & ((1 << lg) - 1)) == 0) {       // gcd | n2 -> solvable
                int r = (n2 >> lg) % m;              // constexpr m: folds
                int x = (m - r) % m;
#pragma unroll
                for (int h = 0; h < 6 - lg; ++h)     // x *= inv(2^(6-lg)) mod m
                    x = (x & 1) ? (x + m) >> 1 : x >> 1;
                const float* wrow = W + (t - 1);
                for (int n1 = x + l*m; n1 < 512; n1 += 64*m)
                    atomicAdd(&dl[n1], wrow[(n1 >> 5) << 9]);
            }
        }
    }
    // ---- Phase B sieve: remaining 480 periods, lane-parallel over t ----
    for (int t = l + 1; t <= 512; t += 64) {
        int g = t & (-t); if (g > 64) g = 64;        // gcd(64, t)
        int lg = __ffs(g) - 1;
        int m = t >> lg;
        if (m <= 8) continue;                        // handled in Phase A
        if (n2 & (g - 1)) continue;
        int r = n2 >> lg;                            // < 64; exact small mod
        while (r >= m) r -= m;
        int x = (r == 0) ? 0 : m - r;
        int k = 6 - lg;
        for (int h = 0; h < k; ++h) x = (x & 1) ? (x + m) >> 1 : x >> 1;
        const float* wrow = W + (t - 1);             // bank = (t-1)%32: conflict-free
        for (int n1 = x; n1 < 512; n1 += m)
            atomicAdd(&dl[n1], wrow[(n1 >> 5) << 9]);
    }
    __syncthreads();

    // ---- forward 512-pt FFT over n1 (identical math to old fft512_fwd) ----
    const float sign = -1.0f;
    float2 v[8], X[8];
#pragma unroll
    for (int q = 0; q < 8; ++q) {
        int n1 = l + 64*q;
        v[q] = make_float2(dl[n1] * sc[n1 >> 5], iv[q]);  // scale folded here
    }
    bfly8(v, sign, X);
#pragma unroll
    for (int r = 0; r < 8; ++r) buf[0][phi(8*l + r)] = X[r];
    __syncthreads();
#pragma unroll
    for (int q = 0; q < 8; ++q) v[q] = buf[0][phi(l + 64*q)];
    int jm = l & 7;
    twiddle_q(v, sign * TWO_PI * (float)jm * (1.0f/64.0f));
    bfly8(v, sign, X);
#pragma unroll
    for (int r = 0; r < 8; ++r) buf[1][phi(((l>>3)<<6) + jm + (r<<3))] = X[r];
    __syncthreads();
#pragma unroll
    for (int q = 0; q < 8; ++q) v[q] = buf[1][phi(l + 64*q)];
    twiddle_q(v, sign * TWO_PI * (float)l * (1.0f/512.0f));
    bfly8(v, sign, X);

    float2* gp = G + b*NSAMP + n2*512;
#pragma unroll
    for (int r = 0; r < 8; ++r) {
        int k1 = l + 64*r;
        int pr = (n2 * k1) & (NSAMP - 1);            // four-step twiddle w_N^{-n2*k1}
        float sa, ca; __sincosf(sign * TWO_PI * (float)pr * (1.0f/32768.0f), &sa, &ca);
        gp[k1] = cmul(X[r], make_float2(ca, sa));
    }
}

// ---------------------------------------------------------------------------
// Kernel 2 (MEGA): per block: 8 spectrum columns = 4 Hermitian pairs.
//   step 1: fwd 64-pt FFT over n2 for each column  -> Z[k1][k2] in LDS
//   step 2: pointwise S = D*I*fv*SCALE in LDS (pair (k, N-k) both in-block;
//           S[N-k] = conj(D*I)*fv*SCALE)
//   step 3: inv 64-pt FFT over k2 per column -> T[k1][n2]; twiddle
//           w_N^{+n2*k1}; store H[n2*512 + k1].
// Columns: group g in [0,64): lows {4g..4g+3}; highs = 512 - low (g=0:
// lows {0..3}, highs {256,511,510,509}; cols 0 and 256 self-paired).
__global__ void mega_kernel(const float2* __restrict__ G,
                            float2* __restrict__ H,
                            const float* __restrict__ filt) {
    const int l  = threadIdx.x;          // 64
    const int cc = l & 7, jj = l >> 3;
    const int s  = blockIdx.x >> 6;
    const int g  = blockIdx.x & 63;
    __shared__ float2 Z[8][65];
    __shared__ float2 buf[576];
    __shared__ float fs[NFR];
    __shared__ int cols[8];

    if (l < NFR) fs[l] = 1.0f/(1.0f + expf(-filt[s*NFR + l]));
    if (l < 8) {
        int col;
        if (l < 4)        col = 4*g + l;
        else if (g == 0)  col = (l == 4) ? 256 : 512 - (l - 4);
        else              col = 512 - 4*g - (l - 4);
        cols[l] = col;
    }
    __syncthreads();

    const float2* sp = G + s * NSAMP;
    const int mycol = cols[cc];
    float2 v[8], X[8];

    // ---- step 1: forward 64-pt FFT (sign=-1) over n2, column mycol ----
#pragma unroll
    for (int q = 0; q < 8; ++q) v[q] = sp[(jj + 8*q)*512 + mycol];
    bfly8(v, -1.0f, X);
#pragma unroll
    for (int r = 0; r < 8; ++r) buf[phi(cc*64 + jj*8 + r)] = X[r];
    __syncthreads();
#pragma unroll
    for (int q = 0; q < 8; ++q) v[q] = buf[phi(cc*64 + jj + 8*q)];
    twiddle_q(v, -TWO_PI * (float)jj * (1.0f/64.0f));
    bfly8(v, -1.0f, X);
#pragma unroll
    for (int r = 0; r < 8; ++r) Z[cc][jj + 8*r] = X[r];   // k2 = jj+8r
    __syncthreads();

    // ---- step 2: pointwise in LDS ----
    const float SCALE = 1.0f / (32768.0f * 181.01933598375618f); // N^{-3/2}
    // general pairs: (c,k2) <-> (c+4, 63-k2), c in [0,4) (skip c==0 when g==0)
#pragma unroll
    for (int it = 0; it < 4; ++it) {
        int c  = l & 3;
        int k2 = (l >> 2) + 16*it;
        if (!(g == 0 && c == 0)) {
            int col = cols[c];
            float2 Zk = Z[c][k2];
            float2 Zr = Z[c+4][63 - k2];
            float2 Zrc = make_float2(Zr.x, -Zr.y);
            float2 D = make_float2(0.5f*(Zk.x + Zrc.x), 0.5f*(Zk.y + Zrc.y));
            float2 df = make_float2(Zk.x - Zrc.x, Zk.y - Zrc.y);
            float2 I = make_float2(0.5f*df.y, -0.5f*df.x);
            int k = col + 512*k2;
            int jjb = (k <= NSAMP - k) ? k : NSAMP - k;
            float fv = 0.0f;
            if (jjb < NSAMP/2) {
                float pos = (jjb + 0.5f) * (1.0f/1024.0f) - 0.5f;
                pos = fminf(fmaxf(pos, 0.0f), 15.0f);
                int i0 = (int)pos;
                float w = pos - (float)i0;
                int i1 = (i0 + 1 > 15) ? 15 : i0 + 1;
                fv = fs[i0]*(1.0f - w) + fs[i1]*w;
            }
            float2 spec = cmul(D, I);
            float gs = fv * SCALE;
            Z[c][k2]        = make_float2( spec.x*gs,  spec.y*gs);
            Z[c+4][63 - k2] = make_float2( spec.x*gs, -spec.y*gs);
        }
    }
    // special self-paired columns for g==0: col 0 (c=0) and col 256 (c=4)
    if (g == 0) {
        if (l <= 32) {            // col 0: k2 <-> (64-k2)&63, k2 in [0,32]
            int k2 = l, k2p = (64 - k2) & 63;
            float2 Zk = Z[0][k2];
            float2 Zr = Z[0][k2p];
            float2 Zrc = make_float2(Zr.x, -Zr.y);
            float2 D = make_float2(0.5f*(Zk.x + Zrc.x), 0.5f*(Zk.y + Zrc.y));
            float2 df = make_float2(Zk.x - Zrc.x, Zk.y - Zrc.y);
            float2 I = make_float2(0.5f*df.y, -0.5f*df.x);
            int k = 512*k2;
            int jjb = (k <= NSAMP - k) ? k : NSAMP - k;
            float fv = 0.0f;
            if (jjb < NSAMP/2) {
                float pos = (jjb + 0.5f) * (1.0f/1024.0f) - 0.5f;
                pos = fminf(fmaxf(pos, 0.0f), 15.0f);
                int i0 = (int)pos;
                float w = pos - (float)i0;
                int i1 = (i0 + 1 > 15) ? 15 : i0 + 1;
                fv = fs[i0]*(1.0f - w) + fs[i1]*w;
            }
            float2 spec = cmul(D, I);
            float gs = fv * SCALE;
            Z[0][k2]  = make_float2( spec.x*gs,  spec.y*gs);
            Z[0][k2p] = make_float2( spec.x*gs, -spec.y*gs);
        }
        if (l < 32) {             // col 256: k2 <-> 63-k2, k2 in [0,32)
            int k2 = l, k2p = 63 - k2;
            float2 Zk = Z[4][k2];
            float2 Zr = Z[4][k2p];
            float2 Zrc = make_float2(Zr.x, -Zr.y);
            float2 D = make_float2(0.5f*(Zk.x + Zrc.x), 0.5f*(Zk.y + Zrc.y));
            float2 df = make_float2(Zk.x - Zrc.x, Zk.y - Zrc.y);
            float2 I = make_float2(0.5f*df.y, -0.5f*df.x);
            int k = 256 + 512*k2;
            int jjb = (k <= NSAMP - k) ? k : NSAMP - k;
            float fv = 0.0f;
            {
                float pos = (jjb + 0.5f) * (1.0f/1024.0f) - 0.5f;
                pos = fminf(fmaxf(pos, 0.0f), 15.0f);
                int i0 = (int)pos;
                float w = pos - (float)i0;
                int i1 = (i0 + 1 > 15) ? 15 : i0 + 1;
                fv = fs[i0]*(1.0f - w) + fs[i1]*w;
            }
            float2 spec = cmul(D, I);
            float gs = fv * SCALE;
            Z[4][k2]  = make_float2( spec.x*gs,  spec.y*gs);
            Z[4][k2p] = make_float2( spec.x*gs, -spec.y*gs);
        }
    }
    __syncthreads();

    // ---- step 3: inverse 64-pt FFT (sign=+1) over k2, column mycol ----
#pragma unroll
    for (int q = 0; q < 8; ++q) v[q] = Z[cc][jj + 8*q];
    bfly8(v, 1.0f, X);
#pragma unroll
    for (int r = 0; r < 8; ++r) buf[phi(cc*64 + jj*8 + r)] = X[r];
    __syncthreads();
#pragma unroll
    for (int q = 0; q < 8; ++q) v[q] = buf[phi(cc*64 + jj + 8*q)];
    twiddle_q(v, TWO_PI * (float)jj * (1.0f/64.0f));
    bfly8(v, 1.0f, X);

    // T[mycol][n2], n2 = jj+8r; twiddle w_N^{+n2*mycol}; store H[n2*512+mycol]
    float2* hp = H + s * NSAMP + mycol;
#pragma unroll
    for (int r = 0; r < 8; ++r) {
        int n2 = jj + 8*r;
        int pr = (n2 * mycol) & (NSAMP - 1);
        float sa, ca; __sincosf(TWO_PI * (float)pr * (1.0f/32768.0f), &sa, &ca);
        hp[n2*512] = cmul(X[r], make_float2(ca, sa));
    }
}

// ---------------------------------------------------------------------------
// Kernel 3: final inverse 512-pt FFT over k1 per (s, n2); input H[n2*512+k1]
// coalesced; NO extra twiddle (already applied in mega); store real part:
// out[s][64*n1 + n2], n1 = j + 64r.
__global__ void fft512_out_kernel(const float2* __restrict__ H,
                                  float* __restrict__ out) {
    const int j  = threadIdx.x;          // 64
    const int s  = blockIdx.x >> 6;
    const int n2 = blockIdx.x & 63;
    __shared__ float2 buf[2][576];
    const float sign = 1.0f;

    const float2* sp = H + s * NSAMP;
    float2 v[8], X[8];
#pragma unroll
    for (int q = 0; q < 8; ++q) v[q] = sp[n2*512 + j + 64*q];

    bfly8(v, sign, X);
#pragma unroll
    for (int r = 0; r < 8; ++r) buf[0][phi(8*j + r)] = X[r];
    __syncthreads();
#pragma unroll
    for (int q = 0; q < 8; ++q) v[q] = buf[0][phi(j + 64*q)];
    int jm = j & 7;
    twiddle_q(v, sign * TWO_PI * (float)jm * (1.0f/64.0f));
    bfly8(v, sign, X);
#pragma unroll
    for (int r = 0; r < 8; ++r) buf[1][phi(((j>>3)<<6) + jm + (r<<3))] = X[r];
    __syncthreads();
#pragma unroll
    for (int q = 0; q < 8; ++q) v[q] = buf[1][phi(j + 64*q)];
    twiddle_q(v, sign * TWO_PI * (float)j * (1.0f/512.0f));
    bfly8(v, sign, X);

    float* op = out + s * NSAMP + n2;
#pragma unroll
    for (int r = 0; r < 8; ++r) op[64*j + 4096*r] = X[r].x;
}

// ---------------------------------------------------------------------------
extern "C" void kernel_launch(void* const* d_in, const int* in_sizes, int n_in,
                              void* d_out, int out_size, void* d_ws, size_t ws_size,
                              hipStream_t stream) {
    const float* impulse = (const float*)d_in[0];   // [8,128]
    const float* dsel    = (const float*)d_in[1];   // [8,512,16]
    const float* damping = (const float*)d_in[2];   // [8,1]
    const float* filt    = (const float*)d_in[3];   // [8,16]
    const float* noise   = (const float*)d_in[4];   // [8,1,32768]
    // d_in[5] (delays, 64 MB): pure structure delays[i,n] = [ (i+1) | n ] — never read.
    float* out = (float*)d_out;                     // [8,32768]

    float2* A = (float2*)d_ws;                      // 2 MB  (G spectrum rows)
    float2* B = A + BATCH * NSAMP;                  // 2 MB  (H)

    // NOTE (R5 lesson): do NOT fuse via hipLaunchCooperativeKernel —
    // grid.sync() on gfx950 costs ~75 µs/barrier. Stream-ordered kernel
    // boundaries ARE the cheap global barrier here.
    // R6: build+fwd-FFT fused via per-(b,n2)-column decomposition
    // (congruence sieve) — 4 passes -> 3 passes, At round-trip eliminated.
    // R7: resubmit of R6 unchanged — previous round was a broker/container
    // infra failure (no compile error, no test result, no rocprof).
    build_fft_kernel <<<dim3(512), dim3(64), 0, stream>>>(impulse, dsel, damping, noise, A);
    mega_kernel      <<<dim3(512), dim3(64), 0, stream>>>(A, B, filt);
    fft512_out_kernel<<<dim3(512), dim3(64), 0, stream>>>(B, out);
}

// Round 3
// 135.186 us; speedup vs baseline: 1.2668x; 1.2668x over previous
//
#include <hip/hip_runtime.h>
#include <math.h>

#define NSAMP 32768   // 2^15 = 512 * 64
#define NDEL  512
#define NFR   16
#define BATCH 8
#define TWO_PI 6.283185307179586f

__device__ __forceinline__ float2 cmul(float2 a, float2 b) {
    return make_float2(a.x*b.x - a.y*b.y, a.x*b.y + a.y*b.x);
}
__device__ __forceinline__ float2 cadd(float2 a, float2 b){ return make_float2(a.x+b.x, a.y+b.y); }
__device__ __forceinline__ float2 csub(float2 a, float2 b){ return make_float2(a.x-b.x, a.y-b.y); }
// multiply by sign*i : fwd(sign=-1) -> -i*z = (y,-x) ; inv(+1) -> +i*z = (-y,x)
__device__ __forceinline__ float2 crot(float2 z, float sign){ return make_float2(-sign*z.y, sign*z.x); }

// LDS index swizzle to break power-of-2 strides (i -> i + i/8)
__device__ __forceinline__ int phi(int i){ return i + (i >> 3); }

__device__ __forceinline__ void bfly8(const float2 v[8], float sign, float2 X[8]) {
    const float S2 = 0.70710678118654752f;
    float2 t0 = cadd(v[0], v[4]), t1 = csub(v[0], v[4]);
    float2 t2 = cadd(v[2], v[6]), t3 = crot(csub(v[2], v[6]), sign);
    float2 E0 = cadd(t0, t2), E1 = cadd(t1, t3), E2 = csub(t0, t2), E3 = csub(t1, t3);
    float2 u0 = cadd(v[1], v[5]), u1 = csub(v[1], v[5]);
    float2 u2 = cadd(v[3], v[7]), u3 = crot(csub(v[3], v[7]), sign);
    float2 O0 = cadd(u0, u2), O1 = cadd(u1, u3), O2 = csub(u0, u2), O3 = csub(u1, u3);
    float2 c1 = make_float2( S2, sign*S2);
    float2 c3 = make_float2(-S2, sign*S2);
    float2 w1o = cmul(c1, O1);
    float2 w2o = crot(O2, sign);
    float2 w3o = cmul(c3, O3);
    X[0]=cadd(E0,O0);  X[4]=csub(E0,O0);
    X[1]=cadd(E1,w1o); X[5]=csub(E1,w1o);
    X[2]=cadd(E2,w2o); X[6]=csub(E2,w2o);
    X[3]=cadd(E3,w3o); X[7]=csub(E3,w3o);
}

__device__ __forceinline__ void twiddle_q(float2 v[8], float ang1) {
    float sa, ca; __sincosf(ang1, &sa, &ca);
    float2 w1 = make_float2(ca, sa), wq = w1;
#pragma unroll
    for (int q = 1; q < 8; ++q) { v[q] = cmul(v[q], wq); wq = cmul(wq, w1); }
}

// ---------------------------------------------------------------------------
// Kernel 1: fused softmax + damping + divisor-sieve + impulse/noise build.
// One wave-block per (b, f, quarter): 512-sample window. Output TRANSPOSED:
// A_T[b][n2][n1] with n = 64*n1 + n2 (thread t = n2 writes 8 consecutive).
//
// R8: reverted from the column-fused build_fft (measured 66.9 µs vs 30.1 µs
// for build+fwd as separate kernels — column decomposition forces per-mark
// W lookups + 450-iteration divergent sieve). Window decomposition keeps
// (a) weight uniform per t (window within one frame -> register), (b) sieve
// divergence <= 8 iterations, (c) softmax computed once per (b,f).
// R8 edits vs r0: LDS-tree reductions (12 barriers + 12 LDS round-trips)
// -> __shfl_xor wave reductions (single-wave block); expf -> __expf.
__global__ void build_kernel(const float* __restrict__ impulse,
                             const float* __restrict__ dsel,
                             const float* __restrict__ damping,
                             const float* __restrict__ noise,
                             float2* __restrict__ At) {
    const int b   = blockIdx.x >> 6;
    const int f   = (blockIdx.x >> 2) & 15;
    const int sub = blockIdx.x & 3;
    const int tid = threadIdx.x;                 // 64 threads = 1 wave
    __shared__ float Wrow[NDEL];
    __shared__ float dl[512];

    float v[8], m = -1e30f;
#pragma unroll
    for (int k = 0; k < 8; ++k) {
        v[k] = dsel[(b*NDEL + tid + 64*k)*NFR + f];
        m = fmaxf(m, v[k]);
    }
    // wave-level max (no LDS, no barriers — single wave)
#pragma unroll
    for (int off = 1; off < 64; off <<= 1) m = fmaxf(m, __shfl_xor(m, off));
    float e[8], s = 0.0f;
#pragma unroll
    for (int k = 0; k < 8; ++k) { e[k] = __expf(v[k] - m); s += e[k]; }
#pragma unroll
    for (int off = 1; off < 64; off <<= 1) s += __shfl_xor(s, off);

    float damp = 1.0f/(1.0f + __expf(-damping[b])) * 0.9999f;
    float scale = damp / s;
#pragma unroll
    for (int k = 0; k < 8; ++k) Wrow[tid + 64*k] = e[k] * scale;
    for (int k = tid; k < 512; k += 64) dl[k] = 0.0f;
    __syncthreads();

    const unsigned start = ((unsigned)f << 11) + ((unsigned)sub << 9);
    const float fstart = (float)start;

    // small t (1..63): block-uniform t, lanes over multiples
    for (unsigned t = 1; t < 64; ++t) {
        float wt = Wrow[t-1];
        unsigned q0 = (unsigned)(__fdividef(fstart, (float)t));
        unsigned n0 = q0 * t;
        while (n0 < start) n0 += t;
        while (n0 >= start + t) n0 -= t;
        for (unsigned i = (n0 - start) + (unsigned)tid * t; i < 512u; i += 64u * t)
            atomicAdd(&dl[i], wt);
    }
    // large t (64..512): lane-parallel over t
    for (unsigned t = 64u + (unsigned)tid; t <= 512u; t += 64u) {
        float wt = Wrow[t-1];
        unsigned q0 = (unsigned)(__fdividef(fstart, (float)t));
        unsigned n0 = q0 * t;
        while (n0 < start) n0 += t;
        while (n0 >= start + t) n0 -= t;
        for (unsigned i = n0 - start; i < 512u; i += t)
            atomicAdd(&dl[i], wt);
    }
    __syncthreads();

    const int n1base = (int)(start >> 6);        // f*32 + sub*8
    float2* op = At + b*NSAMP + tid*512 + n1base;
#pragma unroll
    for (int q = 0; q < 8; ++q) {
        int n = (int)start + tid + 64*q;
        float pos = (n + 0.5f) * (1.0f/256.0f) - 0.5f;
        pos = fminf(fmaxf(pos, 0.0f), 127.0f);
        int i0 = (int)pos;
        float w = pos - (float)i0;
        int i1 = (i0 + 1 > 127) ? 127 : i0 + 1;
        float x0 = impulse[b*128 + i0]; x0 *= x0;
        float x1 = impulse[b*128 + i1]; x1 *= x1;
        float iv = (x0*(1.0f - w) + x1*w) * noise[b*NSAMP + n];
        op[q] = make_float2(dl[tid + 64*q], iv);
    }
}

// ---------------------------------------------------------------------------
// Kernel 2: forward 512-pt FFT over n1 per (s, n2); input transposed (coalesced),
// three radix-8 Stockham stages through LDS, four-step twiddle w_N^{-n2*k1},
// store G[n2*512 + k1].
__global__ void fft512_fwd_kernel(const float2* __restrict__ src,
                                  float2* __restrict__ dst) {
    const int j  = threadIdx.x;          // 64
    const int s  = blockIdx.x >> 6;
    const int n2 = blockIdx.x & 63;
    __shared__ float2 buf[2][576];
    const float sign = -1.0f;

    const float2* sp = src + s * NSAMP;
    float2 v[8], X[8];
#pragma unroll
    for (int q = 0; q < 8; ++q) v[q] = sp[n2*512 + j + 64*q];

    bfly8(v, sign, X);
#pragma unroll
    for (int r = 0; r < 8; ++r) buf[0][phi(8*j + r)] = X[r];
    __syncthreads();
#pragma unroll
    for (int q = 0; q < 8; ++q) v[q] = buf[0][phi(j + 64*q)];
    int jm = j & 7;
    twiddle_q(v, sign * TWO_PI * (float)jm * (1.0f/64.0f));
    bfly8(v, sign, X);
#pragma unroll
    for (int r = 0; r < 8; ++r) buf[1][phi(((j>>3)<<6) + jm + (r<<3))] = X[r];
    __syncthreads();
#pragma unroll
    for (int q = 0; q < 8; ++q) v[q] = buf[1][phi(j + 64*q)];
    twiddle_q(v, sign * TWO_PI * (float)j * (1.0f/512.0f));
    bfly8(v, sign, X);

    float2* dp = dst + s * NSAMP + n2 * 512;
#pragma unroll
    for (int r = 0; r < 8; ++r) {
        int k1 = j + 64*r;
        int pr = (n2 * k1) & (NSAMP - 1);
        float sa, ca; __sincosf(sign * TWO_PI * (float)pr * (1.0f/32768.0f), &sa, &ca);
        dp[k1] = cmul(X[r], make_float2(ca, sa));
    }
}

// ---------------------------------------------------------------------------
// Kernel 3 (MEGA): per block: 8 spectrum columns = 4 Hermitian pairs.
//   step 1: fwd 64-pt FFT over n2 for each column  -> Z[k1][k2] in LDS
//   step 2: pointwise S = D*I*fv*SCALE in LDS (pair (k, N-k) both in-block;
//           S[N-k] = conj(D*I)*fv*SCALE)
//   step 3: inv 64-pt FFT over k2 per column -> T[k1][n2]; twiddle
//           w_N^{+n2*k1}; store H[n2*512 + k1].
// Columns: group g in [0,64): lows {4g..4g+3}; highs = 512 - low (g=0:
// lows {0..3}, highs {256,511,510,509}; cols 0 and 256 self-paired).
__global__ void mega_kernel(const float2* __restrict__ G,
                            float2* __restrict__ H,
                            const float* __restrict__ filt) {
    const int l  = threadIdx.x;          // 64
    const int cc = l & 7, jj = l >> 3;
    const int s  = blockIdx.x >> 6;
    const int g  = blockIdx.x & 63;
    __shared__ float2 Z[8][65];
    __shared__ float2 buf[576];
    __shared__ float fs[NFR];
    __shared__ int cols[8];

    if (l < NFR) fs[l] = 1.0f/(1.0f + __expf(-filt[s*NFR + l]));
    if (l < 8) {
        int col;
        if (l < 4)        col = 4*g + l;
        else if (g == 0)  col = (l == 4) ? 256 : 512 - (l - 4);
        else              col = 512 - 4*g - (l - 4);
        cols[l] = col;
    }
    __syncthreads();

    const float2* sp = G + s * NSAMP;
    const int mycol = cols[cc];
    float2 v[8], X[8];

    // ---- step 1: forward 64-pt FFT (sign=-1) over n2, column mycol ----
#pragma unroll
    for (int q = 0; q < 8; ++q) v[q] = sp[(jj + 8*q)*512 + mycol];
    bfly8(v, -1.0f, X);
#pragma unroll
    for (int r = 0; r < 8; ++r) buf[phi(cc*64 + jj*8 + r)] = X[r];
    __syncthreads();
#pragma unroll
    for (int q = 0; q < 8; ++q) v[q] = buf[phi(cc*64 + jj + 8*q)];
    twiddle_q(v, -TWO_PI * (float)jj * (1.0f/64.0f));
    bfly8(v, -1.0f, X);
#pragma unroll
    for (int r = 0; r < 8; ++r) Z[cc][jj + 8*r] = X[r];   // k2 = jj+8r
    __syncthreads();

    // ---- step 2: pointwise in LDS ----
    const float SCALE = 1.0f / (32768.0f * 181.01933598375618f); // N^{-3/2}
    // general pairs: (c,k2) <-> (c+4, 63-k2), c in [0,4) (skip c==0 when g==0)
#pragma unroll
    for (int it = 0; it < 4; ++it) {
        int c  = l & 3;
        int k2 = (l >> 2) + 16*it;
        if (!(g == 0 && c == 0)) {
            int col = cols[c];
            float2 Zk = Z[c][k2];
            float2 Zr = Z[c+4][63 - k2];
            float2 Zrc = make_float2(Zr.x, -Zr.y);
            float2 D = make_float2(0.5f*(Zk.x + Zrc.x), 0.5f*(Zk.y + Zrc.y));
            float2 df = make_float2(Zk.x - Zrc.x, Zk.y - Zrc.y);
            float2 I = make_float2(0.5f*df.y, -0.5f*df.x);
            int k = col + 512*k2;
            int jjb = (k <= NSAMP - k) ? k : NSAMP - k;
            float fv = 0.0f;
            if (jjb < NSAMP/2) {
                float pos = (jjb + 0.5f) * (1.0f/1024.0f) - 0.5f;
                pos = fminf(fmaxf(pos, 0.0f), 15.0f);
                int i0 = (int)pos;
                float w = pos - (float)i0;
                int i1 = (i0 + 1 > 15) ? 15 : i0 + 1;
                fv = fs[i0]*(1.0f - w) + fs[i1]*w;
            }
            float2 spec = cmul(D, I);
            float gs = fv * SCALE;
            Z[c][k2]        = make_float2( spec.x*gs,  spec.y*gs);
            Z[c+4][63 - k2] = make_float2( spec.x*gs, -spec.y*gs);
        }
    }
    // special self-paired columns for g==0: col 0 (c=0) and col 256 (c=4)
    if (g == 0) {
        if (l <= 32) {            // col 0: k2 <-> (64-k2)&63, k2 in [0,32]
            int k2 = l, k2p = (64 - k2) & 63;
            float2 Zk = Z[0][k2];
            float2 Zr = Z[0][k2p];
            float2 Zrc = make_float2(Zr.x, -Zr.y);
            float2 D = make_float2(0.5f*(Zk.x + Zrc.x), 0.5f*(Zk.y + Zrc.y));
            float2 df = make_float2(Zk.x - Zrc.x, Zk.y - Zrc.y);
            float2 I = make_float2(0.5f*df.y, -0.5f*df.x);
            int k = 512*k2;
            int jjb = (k <= NSAMP - k) ? k : NSAMP - k;
            float fv = 0.0f;
            if (jjb < NSAMP/2) {
                float pos = (jjb + 0.5f) * (1.0f/1024.0f) - 0.5f;
                pos = fminf(fmaxf(pos, 0.0f), 15.0f);
                int i0 = (int)pos;
                float w = pos - (float)i0;
                int i1 = (i0 + 1 > 15) ? 15 : i0 + 1;
                fv = fs[i0]*(1.0f - w) + fs[i1]*w;
            }
            float2 spec = cmul(D, I);
            float gs = fv * SCALE;
            Z[0][k2]  = make_float2( spec.x*gs,  spec.y*gs);
            Z[0][k2p] = make_float2( spec.x*gs, -spec.y*gs);
        }
        if (l < 32) {             // col 256: k2 <-> 63-k2, k2 in [0,32)
            int k2 = l, k2p = 63 - k2;
            float2 Zk = Z[4][k2];
            float2 Zr = Z[4][k2p];
            float2 Zrc = make_float2(Zr.x, -Zr.y);
            float2 D = make_float2(0.5f*(Zk.x + Zrc.x), 0.5f*(Zk.y + Zrc.y));
            float2 df = make_float2(Zk.x - Zrc.x, Zk.y - Zrc.y);
            float2 I = make_float2(0.5f*df.y, -0.5f*df.x);
            int k = 256 + 512*k2;
            int jjb = (k <= NSAMP - k) ? k : NSAMP - k;
            float fv = 0.0f;
            {
                float pos = (jjb + 0.5f) * (1.0f/1024.0f) - 0.5f;
                pos = fminf(fmaxf(pos, 0.0f), 15.0f);
                int i0 = (int)pos;
                float w = pos - (float)i0;
                int i1 = (i0 + 1 > 15) ? 15 : i0 + 1;
                fv = fs[i0]*(1.0f - w) + fs[i1]*w;
            }
            float2 spec = cmul(D, I);
            float gs = fv * SCALE;
            Z[4][k2]  = make_float2( spec.x*gs,  spec.y*gs);
            Z[4][k2p] = make_float2( spec.x*gs, -spec.y*gs);
        }
    }
    __syncthreads();

    // ---- step 3: inverse 64-pt FFT (sign=+1) over k2, column mycol ----
#pragma unroll
    for (int q = 0; q < 8; ++q) v[q] = Z[cc][jj + 8*q];
    bfly8(v, 1.0f, X);
#pragma unroll
    for (int r = 0; r < 8; ++r) buf[phi(cc*64 + jj*8 + r)] = X[r];
    __syncthreads();
#pragma unroll
    for (int q = 0; q < 8; ++q) v[q] = buf[phi(cc*64 + jj + 8*q)];
    twiddle_q(v, TWO_PI * (float)jj * (1.0f/64.0f));
    bfly8(v, 1.0f, X);

    // T[mycol][n2], n2 = jj+8r; twiddle w_N^{+n2*mycol}; store H[n2*512+mycol]
    float2* hp = H + s * NSAMP + mycol;
#pragma unroll
    for (int r = 0; r < 8; ++r) {
        int n2 = jj + 8*r;
        int pr = (n2 * mycol) & (NSAMP - 1);
        float sa, ca; __sincosf(TWO_PI * (float)pr * (1.0f/32768.0f), &sa, &ca);
        hp[n2*512] = cmul(X[r], make_float2(ca, sa));
    }
}

// ---------------------------------------------------------------------------
// Kernel 4: final inverse 512-pt FFT over k1 per (s, n2); input H[n2*512+k1]
// coalesced; NO extra twiddle (already applied in mega); store real part:
// out[s][64*n1 + n2], n1 = j + 64r.
__global__ void fft512_out_kernel(const float2* __restrict__ H,
                                  float* __restrict__ out) {
    const int j  = threadIdx.x;          // 64
    const int s  = blockIdx.x >> 6;
    const int n2 = blockIdx.x & 63;
    __shared__ float2 buf[2][576];
    const float sign = 1.0f;

    const float2* sp = H + s * NSAMP;
    float2 v[8], X[8];
#pragma unroll
    for (int q = 0; q < 8; ++q) v[q] = sp[n2*512 + j + 64*q];

    bfly8(v, sign, X);
#pragma unroll
    for (int r = 0; r < 8; ++r) buf[0][phi(8*j + r)] = X[r];
    __syncthreads();
#pragma unroll
    for (int q = 0; q < 8; ++q) v[q] = buf[0][phi(j + 64*q)];
    int jm = j & 7;
    twiddle_q(v, sign * TWO_PI * (float)jm * (1.0f/64.0f));
    bfly8(v, sign, X);
#pragma unroll
    for (int r = 0; r < 8; ++r) buf[1][phi(((j>>3)<<6) + jm + (r<<3))] = X[r];
    __syncthreads();
#pragma unroll
    for (int q = 0; q < 8; ++q) v[q] = buf[1][phi(j + 64*q)];
    twiddle_q(v, sign * TWO_PI * (float)j * (1.0f/512.0f));
    bfly8(v, sign, X);

    float* op = out + s * NSAMP + n2;
#pragma unroll
    for (int r = 0; r < 8; ++r) op[64*j + 4096*r] = X[r].x;
}

// ---------------------------------------------------------------------------
extern "C" void kernel_launch(void* const* d_in, const int* in_sizes, int n_in,
                              void* d_out, int out_size, void* d_ws, size_t ws_size,
                              hipStream_t stream) {
    const float* impulse = (const float*)d_in[0];   // [8,128]
    const float* dsel    = (const float*)d_in[1];   // [8,512,16]
    const float* damping = (const float*)d_in[2];   // [8,1]
    const float* filt    = (const float*)d_in[3];   // [8,16]
    const float* noise   = (const float*)d_in[4];   // [8,1,32768]
    // d_in[5] (delays, 64 MB): pure structure delays[i,n] = [ (i+1) | n ] — never read.
    float* out = (float*)d_out;                     // [8,32768]

    float2* A = (float2*)d_ws;                      // 2 MB
    float2* B = A + BATCH * NSAMP;                  // 2 MB

    // Cost model (R8, from r0/r2 counter decomposition):
    //   dur_us = harness ws-poison fills (~2 x 41 us, untouchable)
    //          + build+fwd (~30 us) + mega+out (~22 us).
    // Kernel boundaries are CHEAP; the r6/r7 column-fusion regressed
    // build+fwd 30 -> 67 us (per-mark W reads + 450-iter divergent sieve).
    // Keep the windowed 4-kernel structure; do NOT re-fuse via columns.
    build_kernel     <<<dim3(512), dim3(64), 0, stream>>>(impulse, dsel, damping, noise, A);
    fft512_fwd_kernel<<<dim3(512), dim3(64), 0, stream>>>(A, B);
    mega_kernel      <<<dim3(512), dim3(64), 0, stream>>>(B, A, filt);
    fft512_out_kernel<<<dim3(512), dim3(64), 0, stream>>>(A, out);
}